// Round 11
// baseline (87.479 us; speedup 1.0000x reference)
//
#include <hip/hip_runtime.h>
#include <hip/hip_bf16.h>

// Problem constants
#define NTOK 2048
#define TOPK 2
#define HS   512
#define FFN  2048
#define NE   8
#define TASSIGN (NTOK*TOPK)   // 4096
#define PAD  5120             // 4096 + 8*128
#define MAXT128 40
#define MAXT64  72

typedef __attribute__((ext_vector_type(8))) short bf16x8;
typedef __attribute__((ext_vector_type(8))) unsigned short u16x8;
typedef __attribute__((ext_vector_type(4))) float f32x4;

// ws layout (byte offsets); total ~33.6 MB (w1T/w2T eliminated)
static const size_t OFF_XBF  = 0;            // [NTOK*HS] bf16 = 2 MB
static const size_t OFF_H    = 2097152;      // [PAD][FFN] bf16 = 20 MB
static const size_t OFF_OUTV = 23068672;     // [2][PAD][HS] bf16 = 10 MB
static const size_t OFF_RT   = 33554432;     // rowtok [PAD] int
static const size_t OFF_HROF = 33574912;     // hrof [TASSIGN] int
static const size_t OFF_TE128= 33591296;
static const size_t OFF_TR128= 33591456;
static const size_t OFF_TE64 = 33591616;
static const size_t OFF_TR64 = 33591904;

__device__ __forceinline__ unsigned short f2bf(float f) {
    union { __hip_bfloat16 h; unsigned short u; } v;
    v.h = __float2bfloat16(f);
    return v.u;
}

__device__ __forceinline__ float bf2f(unsigned short u) {
    union { unsigned int i; float f; } v;
    v.i = ((unsigned int)u) << 16;
    return v.f;
}

// A-tile swizzle (rows of A / H): chunk ^= row&7  (proven R4-R9)
__device__ __forceinline__ int swza(int r, int byte_off) {
    return byte_off ^ ((r & 7) << 4);
}
// B-tile swizzle over [n][k] LDS: f(n) = (n&7) ^ ((n>>2)&7)
//   reads (n consecutive across lanes): 8 distinct chunks -> 2-way (free)
//   writes (n = 4m+i per lane): f spans all 8 -> ~4-way
__device__ __forceinline__ int swzb(int n, int byte_off) {
    return byte_off ^ ((((n & 7) ^ ((n >> 2) & 7))) << 4);
}

// tanh-approx GELU = x*sigmoid(x*(1.59577 + 0.0713548*x^2)); |err| < 5e-4.
__device__ __forceinline__ float gelu_fast(float x) {
    float z2 = x * fmaf(0.0713548162726f, x * x, 1.5957691216057f);
    float e = __expf(z2);
    return x - __fdividef(x, e + 1.0f);
}

#define GLOAD16(gsrc, ldst) \
    __builtin_amdgcn_global_load_lds((const __attribute__((address_space(1))) void*)(gsrc), \
                                     (__attribute__((address_space(3))) void*)(ldst), 16, 0, 0)

// ---- prep: setup (block 0) + x->bf16 (1024 blocks). No weight transposes. ----
__global__ __launch_bounds__(256) void k_prep(
        const float* __restrict__ x, const int* __restrict__ ei,
        unsigned short* __restrict__ xbf,
        int* __restrict__ rowtok, int* __restrict__ hrof,
        int* __restrict__ te128, int* __restrict__ tr128,
        int* __restrict__ te64, int* __restrict__ tr64) {
    int b = blockIdx.x;
    int tid = threadIdx.x;
    if (b == 0) {
        __shared__ int cnt[NE], offpad[NE], cur[NE];
        for (int i = tid; i < PAD; i += 256) rowtok[i] = 0;
        if (tid < NE) cnt[tid] = 0;
        __syncthreads();
        for (int a = tid; a < TASSIGN; a += 256) atomicAdd(&cnt[ei[a]], 1);
        __syncthreads();
        if (tid == 0) {
            int o = 0, t1 = 0, t2 = 0;
            for (int e = 0; e < NE; e++) {
                offpad[e] = o; cur[e] = 0;
                for (int r = 0; r < cnt[e]; r += 128) { te128[t1] = e; tr128[t1] = o + r; t1++; }
                for (int r = 0; r < cnt[e]; r += 64)  { te64[t2]  = e; tr64[t2]  = o + r; t2++; }
                o += (cnt[e] + 127) / 128 * 128;
            }
            for (; t1 < MAXT128; t1++) te128[t1] = -1;
            for (; t2 < MAXT64;  t2++) te64[t2]  = -1;
        }
        __syncthreads();
        for (int a = tid; a < TASSIGN; a += 256) {
            int e = ei[a];
            int r = atomicAdd(&cur[e], 1);
            int hr = offpad[e] + r;
            rowtok[hr] = a >> 1;       // token = assignment / TOPK
            hrof[a] = hr;
        }
    } else {
        int i = ((b - 1) * 256 + tid) * 4;
        float4 v = *(const float4*)(x + i);
        ushort4 o;
        o.x = f2bf(v.x); o.y = f2bf(v.y); o.z = f2bf(v.z); o.w = f2bf(v.w);
        *(ushort4*)(xbf + i) = o;
    }
}

// ---- grouped GEMM, transpose-free B path ----
// A (bf16, k-contiguous rows): global_load_lds w=16, pre-swizzled source, [m][k] LDS.
// B (f32 [k][n] original weights): reg-staged dwordx4, in-reg cvt+4x4-transpose,
//   ds_write_b64 into [n][k] LDS with swzb. Fragment reads identical to old wT path.
// Sync: R9-proven 2-barrier/step; B-reg data deps + in-order vmcnt retirement make
//   A-landing implicit (B issued after A => B regs ready => A landed).
// G1=true:  H = gelu_fast(gather(A) @ W), bf16 out (kz unused)
// G1=false: bf16 split-K partials of A @ W, blockIdx.z selects K-slice
template<int BM, int BN, int KFULL, int KLOC, bool G1>
__global__ __launch_bounds__(256) void k_gemm(
        const unsigned short* __restrict__ A,
        const float* __restrict__ W,
        unsigned short* __restrict__ outp,
        const int* __restrict__ rowtok,
        const int* __restrict__ te, const int* __restrict__ tr, int N) {
    constexpr int MI = BM / 32, NJ = BN / 32;
    constexpr int PA = BM / 32;                 // A gload sets (256 lanes x 16B)
    constexpr int ABYTES = BM * 64 * 2;
    constexpr int BBYTES = 64 * 64 * 2;         // BN = 64
    constexpr int NSTEP = KLOC / 64;
    static_assert(BN == 64, "BN fixed at 64");
    static_assert(NSTEP % 2 == 0 && NSTEP >= 4, "even steps >= 4");

    int mt = blockIdx.y;
    int e = te[mt];
    if (e < 0) return;
    int hr0 = tr[mt];
    int ct = blockIdx.x;
    int kz = blockIdx.z;
    int k0 = kz * KLOC;

    __shared__ int4 ldsv[(2 * ABYTES + 2 * BBYTES) / 16];
    char* A0 = (char*)ldsv;
    char* A1 = A0 + ABYTES;
    char* B0 = A1 + ABYTES;
    char* B1 = B0 + BBYTES;

    int tid = threadIdx.x;
    int lane = tid & 63, wave = tid >> 6;
    int wm = wave >> 1, wn = wave & 1;

    // A: per-thread pre-swizzled global source (chunk c8 of row r from c8^(r&7))
    const char* asrc[PA];
    int adoff[PA];
#pragma unroll
    for (int p = 0; p < PA; p++) {
        int idx = p * 256 + tid;
        int r = idx >> 3, c8 = idx & 7;
        int c8s = c8 ^ (r & 7);
        size_t row = G1 ? (size_t)rowtok[hr0 + r] : (size_t)(hr0 + r);
        asrc[p] = (const char*)(A + row * KFULL + k0) + c8s * 16;
        adoff[p] = (p * 256 + wave * 64) * 16;   // wave-uniform linear LDS dest
    }
    // B: thread t covers rows k0t..k0t+3, cols n0..n0+3 of the 64x64 f32 tile
    int n0 = (tid & 15) * 4;
    int k0t = (tid >> 4) * 4;
    const float* bsrcf = W + ((size_t)e * KFULL + (size_t)(k0 + k0t)) * N
                           + (size_t)ct * BN + n0;

    f32x4 acc[MI][NJ] = {};
    float4 bregE[4], bregO[4];

    auto issueA = [&](int s, char* Ad) {
        int kb = s * 128;
#pragma unroll
        for (int p = 0; p < PA; p++) GLOAD16(asrc[p] + kb, Ad + adoff[p]);
    };
    auto issueB = [&](int s, float4* br) {
        const float* p = bsrcf + (size_t)s * 64 * N;
#pragma unroll
        for (int j = 0; j < 4; j++) br[j] = *(const float4*)(p + (size_t)j * N);
    };
    // convert + in-reg 4x4 transpose + b64 writes into [n][k] LDS (swzb)
    auto cvtwrite = [&](float4* br, char* Bd) {
        float4 b0 = br[0], b1 = br[1], b2 = br[2], b3 = br[3];
        unsigned long long v0 = (unsigned long long)f2bf(b0.x)
            | ((unsigned long long)f2bf(b1.x) << 16)
            | ((unsigned long long)f2bf(b2.x) << 32)
            | ((unsigned long long)f2bf(b3.x) << 48);
        unsigned long long v1 = (unsigned long long)f2bf(b0.y)
            | ((unsigned long long)f2bf(b1.y) << 16)
            | ((unsigned long long)f2bf(b2.y) << 32)
            | ((unsigned long long)f2bf(b3.y) << 48);
        unsigned long long v2 = (unsigned long long)f2bf(b0.z)
            | ((unsigned long long)f2bf(b1.z) << 16)
            | ((unsigned long long)f2bf(b2.z) << 32)
            | ((unsigned long long)f2bf(b3.z) << 48);
        unsigned long long v3 = (unsigned long long)f2bf(b0.w)
            | ((unsigned long long)f2bf(b1.w) << 16)
            | ((unsigned long long)f2bf(b2.w) << 32)
            | ((unsigned long long)f2bf(b3.w) << 48);
        *(unsigned long long*)(Bd + swzb(n0 + 0, (n0 + 0) * 128 + k0t * 2)) = v0;
        *(unsigned long long*)(Bd + swzb(n0 + 1, (n0 + 1) * 128 + k0t * 2)) = v1;
        *(unsigned long long*)(Bd + swzb(n0 + 2, (n0 + 2) * 128 + k0t * 2)) = v2;
        *(unsigned long long*)(Bd + swzb(n0 + 3, (n0 + 3) * 128 + k0t * 2)) = v3;
    };
    auto compute = [&](const char* As, const char* Bs) {
        __builtin_amdgcn_s_setprio(1);
#pragma unroll
        for (int kk = 0; kk < 64; kk += 32) {
            bf16x8 af[MI], bfv[NJ];
#pragma unroll
            for (int i = 0; i < MI; i++) {
                int ar = wm * (BM / 2) + i * 16 + (lane & 15);
                af[i] = *(const bf16x8*)(As + swza(ar, ar * 128 + kk * 2 + (lane >> 4) * 16));
            }
#pragma unroll
            for (int j = 0; j < NJ; j++) {
                int bc = wn * (BN / 2) + j * 16 + (lane & 15);
                bfv[j] = *(const bf16x8*)(Bs + swzb(bc, bc * 128 + kk * 2 + (lane >> 4) * 16));
            }
#pragma unroll
            for (int i = 0; i < MI; i++)
#pragma unroll
                for (int j = 0; j < NJ; j++)
                    acc[i][j] = __builtin_amdgcn_mfma_f32_16x16x32_bf16(af[i], bfv[j], acc[i][j], 0, 0, 0);
        }
        __builtin_amdgcn_s_setprio(0);
    };
    auto lgkm0 = [&]() { asm volatile("s_waitcnt lgkmcnt(0)" ::: "memory"); };
    auto bar = [&]() {
        __builtin_amdgcn_sched_barrier(0);
        __builtin_amdgcn_s_barrier();
        __builtin_amdgcn_sched_barrier(0);
        asm volatile("" ::: "memory");
    };

    // prologue: steps 0,1 in flight (A before B so B-regs-ready => A landed)
    issueA(0, A0); issueB(0, bregE);
    issueA(1, A1); issueB(1, bregO);
    cvtwrite(bregE, B0);                 // implicit wait on B(0) regs => A(0) landed
    lgkm0(); bar();
    compute(A0, B0);                     // step 0
#pragma unroll 1
    for (int s = 1; s + 1 < NSTEP; s += 2) {
        bar();                           // step s-1 buffers free
        issueA(s + 1, A0); issueB(s + 1, bregE);
        cvtwrite(bregO, B1);             // B(s) -> buf1; waits B(s) => A(s) landed
        lgkm0(); bar();
        compute(A1, B1);                 // step s
        bar();
        issueA(s + 2, A1); issueB(s + 2, bregO);
        cvtwrite(bregE, B0);             // B(s+1) -> buf0
        lgkm0(); bar();
        compute(A0, B0);                 // step s+1
    }
    // tail: step NSTEP-1 (odd -> buf1)
    bar();
    cvtwrite(bregO, B1);
    lgkm0(); bar();
    compute(A1, B1);

    if constexpr (G1) {
#pragma unroll
        for (int i = 0; i < MI; i++)
#pragma unroll
            for (int j = 0; j < NJ; j++)
#pragma unroll
                for (int q = 0; q < 4; q++) {
                    int row = hr0 + wm * (BM / 2) + i * 16 + (lane >> 4) * 4 + q;
                    int col = ct * BN + wn * (BN / 2) + j * 16 + (lane & 15);
                    outp[(size_t)row * N + col] = f2bf(gelu_fast(acc[i][j][q]));
                }
    } else {
        unsigned short* O = outp + (size_t)kz * PAD * HS;
#pragma unroll
        for (int i = 0; i < MI; i++)
#pragma unroll
            for (int j = 0; j < NJ; j++)
#pragma unroll
                for (int q = 0; q < 4; q++) {
                    int row = hr0 + wm * (BM / 2) + i * 16 + (lane >> 4) * 4 + q;
                    int col = ct * BN + wn * (BN / 2) + j * 16 + (lane & 15);
                    O[(size_t)row * N + col] = f2bf(acc[i][j][q]);
                }
    }
}

// ---- combine: sum bf16 split-K partials; y[t] = w0*o0 + w1*o1 ;
//      buffer[t][0..7] fully written (zeros incl.) -> no memset anywhere. ----
__global__ __launch_bounds__(256) void k_combine(
        const unsigned short* __restrict__ outv, const int* __restrict__ ei,
        const float* __restrict__ ew, const int* __restrict__ hrof,
        float* __restrict__ y, float* __restrict__ buf) {
    constexpr size_t SPLIT = (size_t)PAD * HS;   // elements between partials
    int g = blockIdx.x * 256 + threadIdx.x;      // over NTOK*HS/8
    int t = g >> 6, c8 = g & 63;                 // HS/8 = 64 chunks/token
    int a0 = 2 * t, a1 = a0 + 1;
    int h0 = hrof[a0], h1 = hrof[a1];
    u16x8 q0a = *(const u16x8*)(outv + (size_t)h0 * HS + c8 * 8);
    u16x8 q0b = *(const u16x8*)(outv + SPLIT + (size_t)h0 * HS + c8 * 8);
    u16x8 q1a = *(const u16x8*)(outv + (size_t)h1 * HS + c8 * 8);
    u16x8 q1b = *(const u16x8*)(outv + SPLIT + (size_t)h1 * HS + c8 * 8);
    float w0 = ew[a0], w1 = ew[a1];
    float o0[8], o1[8], yy[8];
#pragma unroll
    for (int k = 0; k < 8; k++) {
        o0[k] = bf2f(q0a[k]) + bf2f(q0b[k]);
        o1[k] = bf2f(q1a[k]) + bf2f(q1b[k]);
        yy[k] = w0 * o0[k] + w1 * o1[k];
    }
    float* yp = y + (size_t)t * HS + c8 * 8;
    *(float4*)(yp)     = make_float4(yy[0], yy[1], yy[2], yy[3]);
    *(float4*)(yp + 4) = make_float4(yy[4], yy[5], yy[6], yy[7]);
    int e0 = ei[a0], e1 = ei[a1];
    float* bt = buf + (size_t)t * (NE * HS) + c8 * 8;
#pragma unroll
    for (int e = 0; e < NE; e++) {
        float v[8];
#pragma unroll
        for (int k = 0; k < 8; k++)
            v[k] = (e == e0 ? o0[k] : 0.0f) + (e == e1 ? o1[k] : 0.0f);
        float* be = bt + (size_t)e * HS;
        *(float4*)(be)     = make_float4(v[0], v[1], v[2], v[3]);
        *(float4*)(be + 4) = make_float4(v[4], v[5], v[6], v[7]);
    }
}

extern "C" void kernel_launch(void* const* d_in, const int* in_sizes, int n_in,
                              void* d_out, int out_size, void* d_ws, size_t ws_size,
                              hipStream_t stream) {
    const float* x  = (const float*)d_in[0];
    const float* ew = (const float*)d_in[1];
    const int*   ei = (const int*)d_in[2];
    const float* w1 = (const float*)d_in[3];
    const float* w2 = (const float*)d_in[4];

    char* ws = (char*)d_ws;
    unsigned short* xbf  = (unsigned short*)(ws + OFF_XBF);
    unsigned short* Hb   = (unsigned short*)(ws + OFF_H);
    unsigned short* outv = (unsigned short*)(ws + OFF_OUTV);
    int*            rowtok = (int*)(ws + OFF_RT);
    int*            hrof   = (int*)(ws + OFF_HROF);
    int*            te128  = (int*)(ws + OFF_TE128);
    int*            tr128  = (int*)(ws + OFF_TR128);
    int*            te64   = (int*)(ws + OFF_TE64);
    int*            tr64   = (int*)(ws + OFF_TR64);

    float* y   = (float*)d_out;
    float* buf = (float*)d_out + (size_t)NTOK * HS;

    // prep: setup + x->bf16 only (weight transposes eliminated)
    k_prep<<<1 + 1024, 256, 0, stream>>>(
        x, ei, xbf, rowtok, hrof, te128, tr128, te64, tr64);
    // GEMM1 + fast gelu -> H (bf16): 128x64 tiles, B staged from w1 f32 directly
    k_gemm<128, 64, HS, HS, true><<<dim3(FFN / 64, MAXT128), 256, 0, stream>>>(
        xbf, w1, Hb, rowtok, te128, tr128, FFN);
    // GEMM2 -> bf16 partials: 64x64 tiles, split-K=2, B staged from w2 f32 directly
    k_gemm<64, 64, FFN, FFN / 2, false><<<dim3(HS / 64, MAXT64, 2), 256, 0, stream>>>(
        Hb, w2, outv, rowtok, te64, tr64, HS);
    // combine split-K partials into y and buffer (writes ALL buffer slots)
    k_combine<<<NTOK * HS / 8 / 256, 256, 0, stream>>>(
        outv, ei, ew, hrof, y, buf);
}

// Round 12
// 86.175 us; speedup vs baseline: 1.0151x; 1.0151x over previous
//
#include <hip/hip_runtime.h>
#include <hip/hip_bf16.h>

// Problem constants
#define NTOK 2048
#define TOPK 2
#define HS   512
#define FFN  2048
#define NE   8
#define TASSIGN (NTOK*TOPK)   // 4096
#define PAD  5120             // 4096 + 8*128
#define MAXT128 40
#define MAXT64  72

typedef __attribute__((ext_vector_type(8))) short bf16x8;
typedef __attribute__((ext_vector_type(8))) unsigned short u16x8;
typedef __attribute__((ext_vector_type(4))) float f32x4;

// ws layout (byte offsets); total ~67.15 MB
static const size_t OFF_XBF  = 0;            // [NTOK*HS] bf16
static const size_t OFF_W1T  = 2097152;      // [E][FFN][HS] bf16
static const size_t OFF_W2T  = 18874368;     // [E][HS][FFN] bf16
static const size_t OFF_H    = 35651584;     // [PAD][FFN] bf16
static const size_t OFF_OUTV = 56623104;     // [2][PAD][HS] bf16 (split-K partials)
static const size_t OFF_RT   = 67108864;     // rowtok [PAD] int
static const size_t OFF_HROF = 67129344;     // hrof [TASSIGN] int
static const size_t OFF_TE128= 67145728;
static const size_t OFF_TR128= 67145888;
static const size_t OFF_TE64 = 67146048;
static const size_t OFF_TR64 = 67146336;

__device__ __forceinline__ unsigned short f2bf(float f) {
    union { __hip_bfloat16 h; unsigned short u; } v;
    v.h = __float2bfloat16(f);
    return v.u;
}

__device__ __forceinline__ float bf2f(unsigned short u) {
    union { unsigned int i; float f; } v;
    v.i = ((unsigned int)u) << 16;
    return v.f;
}

__device__ __forceinline__ int swz(int r, int byte_off) {
    return byte_off ^ ((r & 7) << 4);
}

// tanh-approx GELU = x*sigmoid(x*(1.59577 + 0.0713548*x^2)); |err| < 5e-4.
__device__ __forceinline__ float gelu_fast(float x) {
    float z2 = x * fmaf(0.0713548162726f, x * x, 1.5957691216057f);
    float e = __expf(z2);
    return x - __fdividef(x, e + 1.0f);
}

#define GLOAD16(gsrc, ldst) \
    __builtin_amdgcn_global_load_lds((const __attribute__((address_space(1))) void*)(gsrc), \
                                     (__attribute__((address_space(3))) void*)(ldst), 16, 0, 0)

// ---- wide transpose: one 32(row)x64(col) f32 tile -> bf16 [col][row] output.
//      reads float4 x2 (16B/lane), writes ushort4 x2 (16B/lane). ----
__device__ __forceinline__ void dev_tr2(const float* __restrict__ in,
                                        unsigned short* __restrict__ out,
                                        int R, int C, int e, int rb, int cb,
                                        int tid, unsigned short* t /* 32*72 */) {
    const float* ip = in + (size_t)e * R * C + (size_t)rb * C + cb;
    unsigned short* op = out + (size_t)e * C * R + (size_t)cb * R + rb;
    int r = tid >> 3, c8 = (tid & 7) * 8;
    float4 v0 = *(const float4*)(ip + (size_t)r * C + c8);
    float4 v1 = *(const float4*)(ip + (size_t)r * C + c8 + 4);
    ushort4 lo, hi;
    lo.x = f2bf(v0.x); lo.y = f2bf(v0.y); lo.z = f2bf(v0.z); lo.w = f2bf(v0.w);
    hi.x = f2bf(v1.x); hi.y = f2bf(v1.y); hi.z = f2bf(v1.z); hi.w = f2bf(v1.w);
    *(ushort4*)(t + r * 72 + c8)     = lo;
    *(ushort4*)(t + r * 72 + c8 + 4) = hi;
    __syncthreads();
    int c = tid >> 2, r8 = (tid & 3) * 8;
    ushort4 a, b;
    a.x = t[(r8 + 0) * 72 + c]; a.y = t[(r8 + 1) * 72 + c];
    a.z = t[(r8 + 2) * 72 + c]; a.w = t[(r8 + 3) * 72 + c];
    b.x = t[(r8 + 4) * 72 + c]; b.y = t[(r8 + 5) * 72 + c];
    b.z = t[(r8 + 6) * 72 + c]; b.w = t[(r8 + 7) * 72 + c];
    *(ushort4*)(op + (size_t)c * R + r8)     = a;
    *(ushort4*)(op + (size_t)c * R + r8 + 4) = b;
}

// ---- fused prep: setup (1) + x->bf16 (512) + w1T (4096) + w2T (4096) ----
__global__ __launch_bounds__(256) void k_prep(
        const float* __restrict__ x, const float* __restrict__ w1,
        const float* __restrict__ w2, const int* __restrict__ ei,
        unsigned short* __restrict__ xbf, unsigned short* __restrict__ w1T,
        unsigned short* __restrict__ w2T,
        int* __restrict__ rowtok, int* __restrict__ hrof,
        int* __restrict__ te128, int* __restrict__ tr128,
        int* __restrict__ te64, int* __restrict__ tr64) {
    __shared__ unsigned short tsh[32 * 72];
    int b = blockIdx.x;
    int tid = threadIdx.x;
    if (b == 0) {
        __shared__ int cnt[NE], offpad[NE], cur[NE];
        for (int i = tid; i < PAD; i += 256) rowtok[i] = 0;
        if (tid < NE) cnt[tid] = 0;
        __syncthreads();
        for (int a = tid; a < TASSIGN; a += 256) atomicAdd(&cnt[ei[a]], 1);
        __syncthreads();
        if (tid == 0) {
            int o = 0, t1 = 0, t2 = 0;
            for (int e = 0; e < NE; e++) {
                offpad[e] = o; cur[e] = 0;
                for (int r = 0; r < cnt[e]; r += 128) { te128[t1] = e; tr128[t1] = o + r; t1++; }
                for (int r = 0; r < cnt[e]; r += 64)  { te64[t2]  = e; tr64[t2]  = o + r; t2++; }
                o += (cnt[e] + 127) / 128 * 128;
            }
            for (; t1 < MAXT128; t1++) te128[t1] = -1;
            for (; t2 < MAXT64;  t2++) te64[t2]  = -1;
        }
        __syncthreads();
        for (int a = tid; a < TASSIGN; a += 256) {
            int e = ei[a];
            int r = atomicAdd(&cur[e], 1);
            int hr = offpad[e] + r;
            rowtok[hr] = a >> 1;       // token = assignment / TOPK
            hrof[a] = hr;
        }
    } else if (b < 1 + 512) {
        // x->bf16: 8 floats/lane, single 16B store
        int i = ((b - 1) * 256 + tid) * 8;
        float4 v0 = *(const float4*)(x + i);
        float4 v1 = *(const float4*)(x + i + 4);
        u16x8 o;
        o[0] = f2bf(v0.x); o[1] = f2bf(v0.y); o[2] = f2bf(v0.z); o[3] = f2bf(v0.w);
        o[4] = f2bf(v1.x); o[5] = f2bf(v1.y); o[6] = f2bf(v1.z); o[7] = f2bf(v1.w);
        *(u16x8*)(xbf + i) = o;
    } else if (b < 1 + 512 + 4096) {
        // w1 [E][HS=512][FFN=2048] -> w1T [E][FFN][HS]; 512 units/expert
        int blk = b - 513;
        int e = blk >> 9, u = blk & 511;
        dev_tr2(w1, w1T, HS, FFN, e, (u >> 5) * 32, (u & 31) * 64, tid, tsh);
    } else {
        // w2 [E][FFN=2048][HS=512] -> w2T [E][HS][FFN]; 512 units/expert
        int blk = b - 4609;
        int e = blk >> 9, u = blk & 511;
        dev_tr2(w2, w2T, FFN, HS, e, (u >> 3) * 32, (u & 7) * 64, tid, tsh);
    }
}

// ---- grouped GEMM: R9-proven 2-buffer pipeline, counted vmcnt BEFORE barrier ----
// G1=true:  H = gelu_fast(A_gathered @ B^T-layout), bf16 out (kz unused)
// G1=false: bf16 split-K partials, blockIdx.z selects K-slice
template<int BM, int BN, int KFULL, int KLOC, bool G1>
__global__ __launch_bounds__(256) void k_gemm(
        const unsigned short* __restrict__ A,
        const unsigned short* __restrict__ B,
        unsigned short* __restrict__ outp,
        const int* __restrict__ rowtok,
        const int* __restrict__ te, const int* __restrict__ tr, int N) {
    constexpr int MI = BM / 32, NJ = BN / 32;
    constexpr int PA = BM / 32, PB = BN / 32;       // gload sets of 256 lanes x 16B
    constexpr int ABYTES = BM * 64 * 2, BBYTES = BN * 64 * 2;
    constexpr int NSTEP = KLOC / 64;
    static_assert(NSTEP % 2 == 0 && NSTEP >= 4, "even steps >= 4");

    int mt = blockIdx.y;
    int e = te[mt];
    if (e < 0) return;
    int hr0 = tr[mt];
    int ct = blockIdx.x;
    int kz = blockIdx.z;
    int k0 = kz * KLOC;

    __shared__ int4 ldsv[(2 * (ABYTES + BBYTES)) / 16];
    char* A0 = (char*)ldsv;
    char* A1 = A0 + ABYTES;
    char* B0 = A1 + ABYTES;
    char* B1 = B0 + BBYTES;

    int tid = threadIdx.x;
    int lane = tid & 63, wave = tid >> 6;
    int wm = wave >> 1, wn = wave & 1;

    const char* asrc[PA];
    const char* bsrc[PB];
    int adoff[PA], bdoff[PB];
#pragma unroll
    for (int p = 0; p < PA; p++) {
        int idx = p * 256 + tid;
        int r = idx >> 3, c8 = idx & 7;
        int c8s = c8 ^ (r & 7);
        size_t row = G1 ? (size_t)rowtok[hr0 + r] : (size_t)(hr0 + r);
        asrc[p] = (const char*)(A + row * KFULL + k0) + c8s * 16;
        adoff[p] = (p * 256 + wave * 64) * 16;
    }
#pragma unroll
    for (int p = 0; p < PB; p++) {
        int idx = p * 256 + tid;
        int r = idx >> 3, c8 = idx & 7;
        int c8s = c8 ^ (r & 7);
        bsrc[p] = (const char*)(B + ((size_t)e * N + (size_t)ct * BN + r) * KFULL + k0) + c8s * 16;
        bdoff[p] = (p * 256 + wave * 64) * 16;
    }

    f32x4 acc[MI][NJ] = {};

    auto stage = [&](char* Ad, char* Bd, int s) {
        int kb = s * 128;
#pragma unroll
        for (int p = 0; p < PA; p++) GLOAD16(asrc[p] + kb, Ad + adoff[p]);
#pragma unroll
        for (int p = 0; p < PB; p++) GLOAD16(bsrc[p] + kb, Bd + bdoff[p]);
    };
    auto compute = [&](const char* As, const char* Bs) {
#pragma unroll
        for (int kk = 0; kk < 64; kk += 32) {
            bf16x8 af[MI], bfv[NJ];
#pragma unroll
            for (int i = 0; i < MI; i++) {
                int ar = wm * (BM / 2) + i * 16 + (lane & 15);
                af[i] = *(const bf16x8*)(As + swz(ar, ar * 128 + kk * 2 + (lane >> 4) * 16));
            }
#pragma unroll
            for (int j = 0; j < NJ; j++) {
                int bc = wn * (BN / 2) + j * 16 + (lane & 15);
                bfv[j] = *(const bf16x8*)(Bs + swz(bc, bc * 128 + kk * 2 + (lane >> 4) * 16));
            }
#pragma unroll
            for (int i = 0; i < MI; i++)
#pragma unroll
                for (int j = 0; j < NJ; j++)
                    acc[i][j] = __builtin_amdgcn_mfma_f32_16x16x32_bf16(af[i], bfv[j], acc[i][j], 0, 0, 0);
        }
    };
    auto waitv_lps = [&]() {
        if constexpr (PA + PB == 6)      { asm volatile("s_waitcnt vmcnt(6)" ::: "memory"); }
        else if constexpr (PA + PB == 4) { asm volatile("s_waitcnt vmcnt(4)" ::: "memory"); }
        else                             { asm volatile("s_waitcnt vmcnt(0)" ::: "memory"); }
    };
    auto waitv0 = [&]() { asm volatile("s_waitcnt vmcnt(0)" ::: "memory"); };
    auto waitlgkm = [&]() { asm volatile("s_waitcnt lgkmcnt(0)" ::: "memory"); };
    auto bar = [&]() {
        __builtin_amdgcn_sched_barrier(0);
        __builtin_amdgcn_s_barrier();
        __builtin_amdgcn_sched_barrier(0);
        asm volatile("" ::: "memory");
    };

    // prologue: two stages in flight
    stage(A0, B0, 0);
    stage(A1, B1, 1);
#pragma unroll 1
    for (int s = 0; s + 2 < NSTEP; s += 2) {
        waitv_lps(); bar();                 // buf0(step s) ready; step s+1 still in flight
        compute(A0, B0);
        waitlgkm(); bar();                  // all waves done reading buf0
        stage(A0, B0, s + 2);
        waitv_lps(); bar();                 // buf1(step s+1) ready
        compute(A1, B1);
        waitlgkm(); bar();
        if (s + 3 < NSTEP) stage(A1, B1, s + 3);
    }
    // tail
    waitv_lps(); bar();
    compute(A0, B0);
    waitv0(); bar();
    compute(A1, B1);

    if constexpr (G1) {
#pragma unroll
        for (int i = 0; i < MI; i++)
#pragma unroll
            for (int j = 0; j < NJ; j++)
#pragma unroll
                for (int q = 0; q < 4; q++) {
                    int row = hr0 + wm * (BM / 2) + i * 16 + (lane >> 4) * 4 + q;
                    int col = ct * BN + wn * (BN / 2) + j * 16 + (lane & 15);
                    outp[(size_t)row * N + col] = f2bf(gelu_fast(acc[i][j][q]));
                }
    } else {
        unsigned short* O = outp + (size_t)kz * PAD * HS;
#pragma unroll
        for (int i = 0; i < MI; i++)
#pragma unroll
            for (int j = 0; j < NJ; j++)
#pragma unroll
                for (int q = 0; q < 4; q++) {
                    int row = hr0 + wm * (BM / 2) + i * 16 + (lane >> 4) * 4 + q;
                    int col = ct * BN + wn * (BN / 2) + j * 16 + (lane & 15);
                    O[(size_t)row * N + col] = f2bf(acc[i][j][q]);
                }
    }
}

// ---- combine: sum bf16 split-K partials; y[t] = w0*o0 + w1*o1 ;
//      buffer[t][0..7] fully written (zeros incl.) -> no memset anywhere. ----
__global__ __launch_bounds__(256) void k_combine(
        const unsigned short* __restrict__ outv, const int* __restrict__ ei,
        const float* __restrict__ ew, const int* __restrict__ hrof,
        float* __restrict__ y, float* __restrict__ buf) {
    constexpr size_t SPLIT = (size_t)PAD * HS;   // elements between partials
    int g = blockIdx.x * 256 + threadIdx.x;      // over NTOK*HS/8
    int t = g >> 6, c8 = g & 63;                 // HS/8 = 64 chunks/token
    int a0 = 2 * t, a1 = a0 + 1;
    int h0 = hrof[a0], h1 = hrof[a1];
    u16x8 q0a = *(const u16x8*)(outv + (size_t)h0 * HS + c8 * 8);
    u16x8 q0b = *(const u16x8*)(outv + SPLIT + (size_t)h0 * HS + c8 * 8);
    u16x8 q1a = *(const u16x8*)(outv + (size_t)h1 * HS + c8 * 8);
    u16x8 q1b = *(const u16x8*)(outv + SPLIT + (size_t)h1 * HS + c8 * 8);
    float w0 = ew[a0], w1 = ew[a1];
    float o0[8], o1[8], yy[8];
#pragma unroll
    for (int k = 0; k < 8; k++) {
        o0[k] = bf2f(q0a[k]) + bf2f(q0b[k]);
        o1[k] = bf2f(q1a[k]) + bf2f(q1b[k]);
        yy[k] = w0 * o0[k] + w1 * o1[k];
    }
    float* yp = y + (size_t)t * HS + c8 * 8;
    *(float4*)(yp)     = make_float4(yy[0], yy[1], yy[2], yy[3]);
    *(float4*)(yp + 4) = make_float4(yy[4], yy[5], yy[6], yy[7]);
    int e0 = ei[a0], e1 = ei[a1];
    float* bt = buf + (size_t)t * (NE * HS) + c8 * 8;
#pragma unroll
    for (int e = 0; e < NE; e++) {
        float v[8];
#pragma unroll
        for (int k = 0; k < 8; k++)
            v[k] = (e == e0 ? o0[k] : 0.0f) + (e == e1 ? o1[k] : 0.0f);
        float* be = bt + (size_t)e * HS;
        *(float4*)(be)     = make_float4(v[0], v[1], v[2], v[3]);
        *(float4*)(be + 4) = make_float4(v[4], v[5], v[6], v[7]);
    }
}

extern "C" void kernel_launch(void* const* d_in, const int* in_sizes, int n_in,
                              void* d_out, int out_size, void* d_ws, size_t ws_size,
                              hipStream_t stream) {
    const float* x  = (const float*)d_in[0];
    const float* ew = (const float*)d_in[1];
    const int*   ei = (const int*)d_in[2];
    const float* w1 = (const float*)d_in[3];
    const float* w2 = (const float*)d_in[4];

    char* ws = (char*)d_ws;
    unsigned short* xbf  = (unsigned short*)(ws + OFF_XBF);
    unsigned short* w1T  = (unsigned short*)(ws + OFF_W1T);
    unsigned short* w2T  = (unsigned short*)(ws + OFF_W2T);
    unsigned short* Hb   = (unsigned short*)(ws + OFF_H);
    unsigned short* outv = (unsigned short*)(ws + OFF_OUTV);
    int*            rowtok = (int*)(ws + OFF_RT);
    int*            hrof   = (int*)(ws + OFF_HROF);
    int*            te128  = (int*)(ws + OFF_TE128);
    int*            tr128  = (int*)(ws + OFF_TR128);
    int*            te64   = (int*)(ws + OFF_TE64);
    int*            tr64   = (int*)(ws + OFF_TR64);

    float* y   = (float*)d_out;
    float* buf = (float*)d_out + (size_t)NTOK * HS;

    // fused prep: setup + x->bf16 + wide transposes (16B/lane both sides)
    k_prep<<<1 + 512 + 4096 + 4096, 256, 0, stream>>>(
        x, w1, w2, ei, xbf, w1T, w2T, rowtok, hrof, te128, tr128, te64, tr64);
    // GEMM1 + fast gelu -> H (bf16): 128x64 tiles, grid 32 x 40 = 1280 blocks
    k_gemm<128, 64, HS, HS, true><<<dim3(FFN / 64, MAXT128), 256, 0, stream>>>(
        xbf, w1T, Hb, rowtok, te128, tr128, FFN);
    // GEMM2 -> bf16 partials: 64x64 tiles, split-K=2, grid 8 x 72 x 2 = 1152 blocks
    k_gemm<64, 64, FFN, FFN / 2, false><<<dim3(HS / 64, MAXT64, 2), 256, 0, stream>>>(
        Hb, w2T, outv, rowtok, te64, tr64, HS);
    // combine split-K partials into y and buffer (writes ALL buffer slots)
    k_combine<<<NTOK * HS / 8 / 256, 256, 0, stream>>>(
        outv, ei, ew, hrof, y, buf);
}